// Round 4
// baseline (3148.908 us; speedup 1.0000x reference)
//
#include <hip/hip_runtime.h>
#include <math.h>

#define NPTS 131072

typedef short s16x8 __attribute__((ext_vector_type(8)));
typedef short s16x4 __attribute__((ext_vector_type(4)));
typedef float f32x4 __attribute__((ext_vector_type(4)));

struct Planes9 { const float* p[9]; };

__device__ __forceinline__ float sp100(float h) {
    float z = 100.0f * h;
    return (fmaxf(z, 0.0f) + log1pf(__expf(-fabsf(z)))) * 0.01f;
}

__device__ __forceinline__ short f2bf(float f) {
    union { float f; unsigned u; } a; a.f = f;
    unsigned u = a.u;
    return (short)((u + 0x7FFFu + ((u >> 16) & 1u)) >> 16);
}
__device__ __forceinline__ float bf2f(short h) {
    union { unsigned u; float f; } a; a.u = ((unsigned)(unsigned short)h) << 16;
    return a.f;
}

__device__ __forceinline__ f32x4 mm(s16x8 a, s16x8 b, f32x4 c) {
    return __builtin_amdgcn_mfma_f32_16x16x32_bf16(a, b, c, 0, 0, 0);
}

// ======================= gather kernel: 4 threads/point, 16 ch each ====================
// Writes feat bf16 hi/lo for a chunk of points, plane-major: [9][CH][64] shorts.
__global__ __launch_bounds__(256) void gather_kernel(
    const float* __restrict__ x, const float* __restrict__ tpl,
    short* __restrict__ fH, short* __restrict__ fL, int p0, int CH)
{
    const int tid = blockIdx.x * 256 + threadIdx.x;
    const int ptl = tid >> 2, q = tid & 3;
    const int pt = p0 + ptl;
    const float xc0 = x[pt*3+0], xc1 = x[pt*3+1], xc2 = x[pt*3+2];
    const size_t pstride = (size_t)CH * 64;
    #pragma unroll 1
    for (int pl = 0; pl < 9; ++pl) {
        const int grp = (pl >= 6) ? 2 : (pl >= 3 ? 1 : 0);
        const int r = pl - grp * 3;
        const int L = 64 << r;
        const float u = (grp == 2) ? xc1 : xc0;
        const float v = (grp == 0) ? xc1 : xc2;
        float ix = (u + 1.0f) * 0.5f * (float)(L - 1);
        float iy = (v + 1.0f) * 0.5f * (float)(L - 1);
        float ix0 = floorf(ix), iy0 = floorf(iy);
        float wx = ix - ix0, wy = iy - iy0;
        int x0 = (int)fminf(fmaxf(ix0, 0.f), (float)(L-1));
        int x1 = (int)fminf(fmaxf(ix0+1.f, 0.f), (float)(L-1));
        int y0 = (int)fminf(fmaxf(iy0, 0.f), (float)(L-1));
        int y1 = (int)fminf(fmaxf(iy0+1.f, 0.f), (float)(L-1));
        float wnw = (1.f-wx)*(1.f-wy), wne = wx*(1.f-wy), wsw = (1.f-wx)*wy, wse = wx*wy;

        size_t poff = (size_t)grp * 5505024 + (r == 0 ? 0u : (r == 1 ? 262144u : 1310720u));
        const float* P = tpl + poff;
        const float4* c00 = (const float4*)(P + ((size_t)(y0*L + x0)*64 + q*16));
        const float4* c01 = (const float4*)(P + ((size_t)(y0*L + x1)*64 + q*16));
        const float4* c10 = (const float4*)(P + ((size_t)(y1*L + x0)*64 + q*16));
        const float4* c11 = (const float4*)(P + ((size_t)(y1*L + x1)*64 + q*16));
        float f[16];
        #pragma unroll
        for (int qq = 0; qq < 4; ++qq) {
            float4 a = c00[qq], b = c01[qq], c = c10[qq], d = c11[qq];
            f[qq*4+0] = wnw*a.x + wne*b.x + wsw*c.x + wse*d.x;
            f[qq*4+1] = wnw*a.y + wne*b.y + wsw*c.y + wse*d.y;
            f[qq*4+2] = wnw*a.z + wne*b.z + wsw*c.z + wse*d.z;
            f[qq*4+3] = wnw*a.w + wne*b.w + wsw*c.w + wse*d.w;
        }
        s16x8 hi8[2], lo8[2];
        #pragma unroll
        for (int e = 0; e < 16; ++e) {
            float vv = f[e];
            short hb = f2bf(vv);
            hi8[e >> 3][e & 7] = hb;
            lo8[e >> 3][e & 7] = f2bf(vv - bf2f(hb));
        }
        size_t o = (size_t)pl * pstride + (size_t)ptl * 64 + q * 16;
        *(s16x8*)(fH + o)     = hi8[0];
        *(s16x8*)(fH + o + 8) = hi8[1];
        *(s16x8*)(fL + o)     = lo8[0];
        *(s16x8*)(fL + o + 8) = lo8[1];
    }
}

// ======================= MLP kernel: 128 points / block, 4 waves =======================
// L1 B-operand straight from global feat (no LDS, no barriers); L2/L3 as validated in R2.
__global__ __launch_bounds__(256, 2) void mlp_kernel(
    const short* __restrict__ fH, const short* __restrict__ fL,
    const short* __restrict__ W1h, const short* __restrict__ W1l,
    const short* __restrict__ W2h, const short* __restrict__ W2l,
    const short* __restrict__ Wlh, const short* __restrict__ Wll,
    const float* __restrict__ b1, const float* __restrict__ b2, const float* __restrict__ bl,
    float* __restrict__ out, int p0, int CH)
{
    __shared__ __align__(16) char smem[65536];   // hB [128 pt][256 k] bf16, swizzled
    const int t = threadIdx.x, blk = blockIdx.x;
    const int w = t >> 6, ln = t & 63, s = ln & 15, g = ln >> 4;
    const int swz = (s & 7) << 4;
    const size_t pstride = (size_t)CH * 64;

    f32x4 acc[8][4];
    const f32x4 fz = {0.f, 0.f, 0.f, 0.f};
    #pragma unroll
    for (int mt = 0; mt < 8; ++mt)
        #pragma unroll
        for (int j = 0; j < 4; ++j) acc[mt][j] = fz;

    const size_t ptl = (size_t)blk * 128;   // local (chunk) point base

    // ---------------- Layer 1: K = 576 (18 steps of 32), 3-term split ----------------
    #pragma unroll 2
    for (int ks = 0; ks < 18; ++ks) {
        const int pl = ks >> 1;
        const int kin = (ks & 1) * 32 + g * 8;
        const short* bH = fH + (size_t)pl * pstride + (ptl + s) * 64 + kin;
        const short* bL = fL + (size_t)pl * pstride + (ptl + s) * 64 + kin;
        s16x8 Ah[4], Al[4];
        #pragma unroll
        for (int j = 0; j < 4; ++j) {
            size_t ro = (size_t)((4*j + w)*16 + s) * 576 + (size_t)(ks*32 + g*8);
            Ah[j] = *(const s16x8*)(W1h + ro);
            Al[j] = *(const s16x8*)(W1l + ro);
        }
        #pragma unroll
        for (int mt = 0; mt < 8; ++mt) {
            s16x8 Bh = *(const s16x8*)(bH + mt * 1024);
            s16x8 Bl = *(const s16x8*)(bL + mt * 1024);
            #pragma unroll
            for (int j = 0; j < 4; ++j) {
                acc[mt][j] = mm(Ah[j], Bh, acc[mt][j]);
                acc[mt][j] = mm(Ah[j], Bl, acc[mt][j]);
                acc[mt][j] = mm(Al[j], Bh, acc[mt][j]);
            }
        }
    }

    // ======== bias + softplus, stage h1 (bf16) to hB [128 m][256 k] ========
    #pragma unroll
    for (int j = 0; j < 4; ++j) {
        f32x4 bv = *(const f32x4*)(b1 + (4*j + w)*16 + g*4);
        #pragma unroll
        for (int mt = 0; mt < 8; ++mt) {
            f32x4 a = acc[mt][j];
            s16x4 hq;
            hq[0] = f2bf(sp100(a[0] + bv[0]));
            hq[1] = f2bf(sp100(a[1] + bv[1]));
            hq[2] = f2bf(sp100(a[2] + bv[2]));
            hq[3] = f2bf(sp100(a[3] + bv[3]));
            int off = (mt*16 + s)*512 + ((((4*j + w)*32) + g*8) ^ swz);
            *(s16x4*)(smem + off) = hq;
        }
    }
    #pragma unroll
    for (int mt = 0; mt < 8; ++mt)
        #pragma unroll
        for (int j = 0; j < 4; ++j) acc[mt][j] = fz;
    __syncthreads();

    // ---------------- Layer 2: K = 256, split weights (2-term) ----------------
    #pragma unroll 1
    for (int ks = 0; ks < 8; ++ks) {
        s16x8 Ah[4], Al[4];
        #pragma unroll
        for (int j = 0; j < 4; ++j) {
            size_t ro = (size_t)((4*j + w)*16 + s) * 256 + (size_t)(ks*32 + g*8);
            Ah[j] = *(const s16x8*)(W2h + ro);
            Al[j] = *(const s16x8*)(W2l + ro);
        }
        #pragma unroll
        for (int mt = 0; mt < 8; ++mt) {
            int off = (mt*16 + s)*512 + ((ks*64 + g*16) ^ swz);
            s16x8 B = *(s16x8*)(smem + off);
            #pragma unroll
            for (int j = 0; j < 4; ++j) {
                acc[mt][j] = mm(Ah[j], B, acc[mt][j]);
                acc[mt][j] = mm(Al[j], B, acc[mt][j]);
            }
        }
    }
    __syncthreads();   // all hB reads done before overwrite with h2

    // ======== bias + softplus, stage h2 ========
    #pragma unroll
    for (int j = 0; j < 4; ++j) {
        f32x4 bv = *(const f32x4*)(b2 + (4*j + w)*16 + g*4);
        #pragma unroll
        for (int mt = 0; mt < 8; ++mt) {
            f32x4 a = acc[mt][j];
            s16x4 hq;
            hq[0] = f2bf(sp100(a[0] + bv[0]));
            hq[1] = f2bf(sp100(a[1] + bv[1]));
            hq[2] = f2bf(sp100(a[2] + bv[2]));
            hq[3] = f2bf(sp100(a[3] + bv[3]));
            int off = (mt*16 + s)*512 + ((((4*j + w)*32) + g*8) ^ swz);
            *(s16x4*)(smem + off) = hq;
        }
    }
    __syncthreads();

    // ---------------- Layer 3: Wl padded to 128 rows; wave w does tiles w, 4+w --------
    f32x4 acc3[8][2];
    #pragma unroll
    for (int mt = 0; mt < 8; ++mt) { acc3[mt][0] = fz; acc3[mt][1] = fz; }
    #pragma unroll 1
    for (int ks = 0; ks < 8; ++ks) {
        s16x8 Ah[2], Al[2];
        #pragma unroll
        for (int j = 0; j < 2; ++j) {
            size_t ro = (size_t)((4*j + w)*16 + s) * 256 + (size_t)(ks*32 + g*8);
            Ah[j] = *(const s16x8*)(Wlh + ro);
            Al[j] = *(const s16x8*)(Wll + ro);
        }
        #pragma unroll
        for (int mt = 0; mt < 8; ++mt) {
            int off = (mt*16 + s)*512 + ((ks*64 + g*16) ^ swz);
            s16x8 B = *(s16x8*)(smem + off);
            #pragma unroll
            for (int j = 0; j < 2; ++j) {
                acc3[mt][j] = mm(Ah[j], B, acc3[mt][j]);
                acc3[mt][j] = mm(Al[j], B, acc3[mt][j]);
            }
        }
    }

    // ---------------- output: feat (P,64) + dsdf (P,1) ----------------
    {
        f32x4 bv = *(const f32x4*)(bl + w*16 + g*4);
        #pragma unroll
        for (int mt = 0; mt < 8; ++mt) {
            size_t p = (size_t)p0 + ptl + (size_t)(mt*16 + s);
            f32x4 o = acc3[mt][0];
            o[0] += bv[0]; o[1] += bv[1]; o[2] += bv[2]; o[3] += bv[3];
            *(f32x4*)(out + p*64 + (size_t)(w*16 + g*4)) = o;
            if (w == 0 && g == 0)
                out[(size_t)NPTS*64 + p] = acc3[mt][1][0] + bl[64];
        }
    }
}

// ================= fallback fused kernel (validated R2 path) ==============
__global__ __launch_bounds__(256, 2) void fused_kernel(
    const float* __restrict__ x, Planes9 pls, const float* __restrict__ tpl, int use_t,
    const short* __restrict__ W1h, const short* __restrict__ W1l,
    const short* __restrict__ W2h, const short* __restrict__ W2l,
    const short* __restrict__ Wlh, const short* __restrict__ Wll,
    const float* __restrict__ b1, const float* __restrict__ b2, const float* __restrict__ bl,
    float* __restrict__ out)
{
    __shared__ __align__(16) char smem[65536];
    __shared__ float xs[384];
    const int t = threadIdx.x, blk = blockIdx.x;
    for (int i = t; i < 384; i += 256) xs[i] = x[(size_t)blk * 384 + i];

    const int w = t >> 6, ln = t & 63, s = ln & 15, g = ln >> 4;
    const int swz = (s & 7) << 4;
    const int pt = t & 127, kh = t >> 7;
    const int ptswz = (pt & 7) << 4;

    f32x4 acc[8][4];
    const f32x4 fz = {0.f, 0.f, 0.f, 0.f};
    #pragma unroll
    for (int mt = 0; mt < 8; ++mt)
        #pragma unroll
        for (int j = 0; j < 4; ++j) acc[mt][j] = fz;

    __syncthreads();

    #pragma unroll 1
    for (int pl = 0; pl < 9; ++pl) {
        const int grp = (pl >= 6) ? 2 : (pl >= 3 ? 1 : 0);
        const int r = pl - grp * 3;
        const int L = 64 << r;
        float u, v;
        { float xc0 = xs[pt*3+0], xc1 = xs[pt*3+1], xc2 = xs[pt*3+2];
          u = (grp == 2) ? xc1 : xc0;
          v = (grp == 0) ? xc1 : xc2; }
        float ix = (u + 1.0f) * 0.5f * (float)(L - 1);
        float iy = (v + 1.0f) * 0.5f * (float)(L - 1);
        float ix0 = floorf(ix), iy0 = floorf(iy);
        float wx = ix - ix0, wy = iy - iy0;
        int x0 = (int)fminf(fmaxf(ix0, 0.f), (float)(L-1));
        int x1 = (int)fminf(fmaxf(ix0+1.f, 0.f), (float)(L-1));
        int y0 = (int)fminf(fmaxf(iy0, 0.f), (float)(L-1));
        int y1 = (int)fminf(fmaxf(iy0+1.f, 0.f), (float)(L-1));
        float wnw = (1.f-wx)*(1.f-wy), wne = wx*(1.f-wy), wsw = (1.f-wx)*wy, wse = wx*wy;

        float f[32];
        if (use_t) {
            size_t poff = (size_t)grp * 5505024 + (r == 0 ? 0u : (r == 1 ? 262144u : 1310720u));
            const float* P = tpl + poff;
            const float4* c00 = (const float4*)(P + ((size_t)(y0*L + x0)*64 + kh*32));
            const float4* c01 = (const float4*)(P + ((size_t)(y0*L + x1)*64 + kh*32));
            const float4* c10 = (const float4*)(P + ((size_t)(y1*L + x0)*64 + kh*32));
            const float4* c11 = (const float4*)(P + ((size_t)(y1*L + x1)*64 + kh*32));
            #pragma unroll
            for (int qq = 0; qq < 8; ++qq) {
                float4 a = c00[qq], b = c01[qq], c = c10[qq], d = c11[qq];
                f[qq*4+0] = wnw*a.x + wne*b.x + wsw*c.x + wse*d.x;
                f[qq*4+1] = wnw*a.y + wne*b.y + wsw*c.y + wse*d.y;
                f[qq*4+2] = wnw*a.z + wne*b.z + wsw*c.z + wse*d.z;
                f[qq*4+3] = wnw*a.w + wne*b.w + wsw*c.w + wse*d.w;
            }
        } else {
            const float* P = pls.p[pl];
            const int i00 = y0*L+x0, i01 = y0*L+x1, i10 = y1*L+x0, i11 = y1*L+x1;
            #pragma unroll 8
            for (int c = 0; c < 32; ++c) {
                const float* pc = P + (size_t)(kh*32 + c) * L * L;
                f[c] = wnw*pc[i00] + wne*pc[i01] + wsw*pc[i10] + wse*pc[i11];
            }
        }
        #pragma unroll
        for (int qq = 0; qq < 4; ++qq) {
            s16x8 hi8, lo8;
            #pragma unroll
            for (int e = 0; e < 8; ++e) {
                float vv = f[qq*8+e];
                short hb = f2bf(vv);
                hi8[e] = hb;
                lo8[e] = f2bf(vv - bf2f(hb));
            }
            int off = pt*128 + ((kh*64 + qq*16) ^ ptswz);
            *(s16x8*)(smem + off)         = hi8;
            *(s16x8*)(smem + 16384 + off) = lo8;
        }
        __syncthreads();

        #pragma unroll
        for (int ks = 0; ks < 2; ++ks) {
            s16x8 Ah[4], Al[4];
            #pragma unroll
            for (int j = 0; j < 4; ++j) {
                size_t ro = (size_t)((4*j + w)*16 + s) * 576 + (size_t)(pl*64 + ks*32 + g*8);
                Ah[j] = *(const s16x8*)(W1h + ro);
                Al[j] = *(const s16x8*)(W1l + ro);
            }
            #pragma unroll
            for (int mt = 0; mt < 8; ++mt) {
                int off = (mt*16 + s)*128 + ((ks*64 + g*16) ^ swz);
                s16x8 Bh = *(s16x8*)(smem + off);
                s16x8 Bl = *(s16x8*)(smem + 16384 + off);
                #pragma unroll
                for (int j = 0; j < 4; ++j) {
                    acc[mt][j] = mm(Ah[j], Bh, acc[mt][j]);
                    acc[mt][j] = mm(Ah[j], Bl, acc[mt][j]);
                    acc[mt][j] = mm(Al[j], Bh, acc[mt][j]);
                }
            }
        }
        __syncthreads();
    }

    #pragma unroll
    for (int j = 0; j < 4; ++j) {
        f32x4 bv = *(const f32x4*)(b1 + (4*j + w)*16 + g*4);
        #pragma unroll
        for (int mt = 0; mt < 8; ++mt) {
            f32x4 a = acc[mt][j];
            s16x4 hq;
            hq[0] = f2bf(sp100(a[0] + bv[0]));
            hq[1] = f2bf(sp100(a[1] + bv[1]));
            hq[2] = f2bf(sp100(a[2] + bv[2]));
            hq[3] = f2bf(sp100(a[3] + bv[3]));
            int off = (mt*16 + s)*512 + ((((4*j + w)*32) + g*8) ^ swz);
            *(s16x4*)(smem + off) = hq;
        }
    }
    #pragma unroll
    for (int mt = 0; mt < 8; ++mt)
        #pragma unroll
        for (int j = 0; j < 4; ++j) acc[mt][j] = fz;
    __syncthreads();

    #pragma unroll 1
    for (int ks = 0; ks < 8; ++ks) {
        s16x8 Ah[4], Al[4];
        #pragma unroll
        for (int j = 0; j < 4; ++j) {
            size_t ro = (size_t)((4*j + w)*16 + s) * 256 + (size_t)(ks*32 + g*8);
            Ah[j] = *(const s16x8*)(W2h + ro);
            Al[j] = *(const s16x8*)(W2l + ro);
        }
        #pragma unroll
        for (int mt = 0; mt < 8; ++mt) {
            int off = (mt*16 + s)*512 + ((ks*64 + g*16) ^ swz);
            s16x8 B = *(s16x8*)(smem + off);
            #pragma unroll
            for (int j = 0; j < 4; ++j) {
                acc[mt][j] = mm(Ah[j], B, acc[mt][j]);
                acc[mt][j] = mm(Al[j], B, acc[mt][j]);
            }
        }
    }
    __syncthreads();

    #pragma unroll
    for (int j = 0; j < 4; ++j) {
        f32x4 bv = *(const f32x4*)(b2 + (4*j + w)*16 + g*4);
        #pragma unroll
        for (int mt = 0; mt < 8; ++mt) {
            f32x4 a = acc[mt][j];
            s16x4 hq;
            hq[0] = f2bf(sp100(a[0] + bv[0]));
            hq[1] = f2bf(sp100(a[1] + bv[1]));
            hq[2] = f2bf(sp100(a[2] + bv[2]));
            hq[3] = f2bf(sp100(a[3] + bv[3]));
            int off = (mt*16 + s)*512 + ((((4*j + w)*32) + g*8) ^ swz);
            *(s16x4*)(smem + off) = hq;
        }
    }
    __syncthreads();

    f32x4 acc3[8][2];
    #pragma unroll
    for (int mt = 0; mt < 8; ++mt) { acc3[mt][0] = fz; acc3[mt][1] = fz; }
    #pragma unroll 1
    for (int ks = 0; ks < 8; ++ks) {
        s16x8 Ah[2], Al[2];
        #pragma unroll
        for (int j = 0; j < 2; ++j) {
            size_t ro = (size_t)((4*j + w)*16 + s) * 256 + (size_t)(ks*32 + g*8);
            Ah[j] = *(const s16x8*)(Wlh + ro);
            Al[j] = *(const s16x8*)(Wll + ro);
        }
        #pragma unroll
        for (int mt = 0; mt < 8; ++mt) {
            int off = (mt*16 + s)*512 + ((ks*64 + g*16) ^ swz);
            s16x8 B = *(s16x8*)(smem + off);
            #pragma unroll
            for (int j = 0; j < 2; ++j) {
                acc3[mt][j] = mm(Ah[j], B, acc3[mt][j]);
                acc3[mt][j] = mm(Al[j], B, acc3[mt][j]);
            }
        }
    }

    {
        f32x4 bv = *(const f32x4*)(bl + w*16 + g*4);
        #pragma unroll
        for (int mt = 0; mt < 8; ++mt) {
            size_t p = (size_t)blk*128 + (size_t)(mt*16 + s);
            f32x4 o = acc3[mt][0];
            o[0] += bv[0]; o[1] += bv[1]; o[2] += bv[2]; o[3] += bv[3];
            *(f32x4*)(out + p*64 + (size_t)(w*16 + g*4)) = o;
            if (w == 0 && g == 0)
                out[(size_t)NPTS*64 + p] = acc3[mt][1][0] + bl[64];
        }
    }
}

// ---------------- weight-norm + bf16 hi/lo split (row-major n x k) -------
__global__ __launch_bounds__(64) void prep_weights(
    const float* __restrict__ v1, const float* __restrict__ g1,
    const float* __restrict__ v2, const float* __restrict__ g2,
    const float* __restrict__ vl, const float* __restrict__ gl,
    short* __restrict__ W1h, short* __restrict__ W1l,
    short* __restrict__ W2h, short* __restrict__ W2l,
    short* __restrict__ Wlh, short* __restrict__ Wll)
{
    int i = blockIdx.x, t = threadIdx.x;
    const float* src; float gv; int K; short *dh, *dl; size_t ro;
    if (i < 256)      { src = v1 + (size_t)i*576; gv = g1[i]; K = 576; dh = W1h; dl = W1l; ro = (size_t)i*576; }
    else if (i < 512) { int rr = i-256; src = v2 + (size_t)rr*256; gv = g2[rr]; K = 256; dh = W2h; dl = W2l; ro = (size_t)rr*256; }
    else {
        int rr = i-512;
        K = 256; dh = Wlh; dl = Wll; ro = (size_t)rr*256;
        if (rr >= 65) {
            for (int k = t; k < 256; k += 64) { dh[ro+k] = 0; dl[ro+k] = 0; }
            return;
        }
        src = vl + (size_t)rr*256; gv = gl[rr];
    }
    float ssum = 0.f;
    for (int k = t; k < K; k += 64) { float wv = src[k]; ssum += wv*wv; }
    #pragma unroll
    for (int off = 32; off > 0; off >>= 1) ssum += __shfl_xor(ssum, off, 64);
    float sc = gv / sqrtf(ssum);
    for (int k = t; k < K; k += 64) {
        float wv = src[k] * sc;
        short hb = f2bf(wv);
        dh[ro + k] = hb;
        dl[ro + k] = f2bf(wv - bf2f(hb));
    }
}

// ---------------- planes (C,H,W) -> (H,W,C) fp32 ----------------
__global__ __launch_bounds__(256) void transpose_planes(Planes9 pls, float* __restrict__ dst)
{
    __shared__ float tile[64 * 65];
    int b = blockIdx.x;
    int g = b / 1344, rem = b % 1344;
    int r, t2;
    if (rem < 64)       { r = 0; t2 = rem; }
    else if (rem < 320) { r = 1; t2 = rem - 64; }
    else                { r = 2; t2 = rem - 320; }
    int L = 64 << r;
    int wt = L >> 6;
    int y = t2 / wt, xt = t2 % wt;
    const float* sp = pls.p[g * 3 + r];
    float* dp = dst + (size_t)g * 5505024 + (r == 0 ? 0 : (r == 1 ? 262144 : 1310720));
    int t = threadIdx.x;
    int rowbase = y * L + xt * 64;
    {
        int xi = t & 63, cq = t >> 6;
        #pragma unroll
        for (int cc = 0; cc < 16; ++cc) {
            int c = cq * 16 + cc;
            tile[c * 65 + xi] = sp[(size_t)c * L * L + rowbase + xi];
        }
    }
    __syncthreads();
    {
        int ci = t & 63, xq = t >> 6;
        #pragma unroll
        for (int xx = 0; xx < 16; ++xx) {
            int xcol = xq * 16 + xx;
            dp[(size_t)(rowbase + xcol) * 64 + ci] = tile[ci * 65 + xcol];
        }
    }
}

extern "C" void kernel_launch(void* const* d_in, const int* in_sizes, int n_in,
                              void* d_out, int out_size, void* d_ws, size_t ws_size,
                              hipStream_t stream)
{
    const float* x = (const float*)d_in[0];
    Planes9 pls;
    for (int i = 0; i < 9; ++i) pls.p[i] = (const float*)d_in[1 + i];
    const float* v1 = (const float*)d_in[10];
    const float* g1 = (const float*)d_in[11];
    const float* b1 = (const float*)d_in[12];
    const float* v2 = (const float*)d_in[13];
    const float* g2 = (const float*)d_in[14];
    const float* b2 = (const float*)d_in[15];
    const float* vl = (const float*)d_in[16];
    const float* gl = (const float*)d_in[17];
    const float* bl = (const float*)d_in[18];

    short* ws16 = (short*)d_ws;
    short* W1h = ws16;                    // 256*576
    short* W1l = ws16 + 147456;
    short* W2h = ws16 + 294912;           // 256*256
    short* W2l = ws16 + 360448;
    short* Wlh = ws16 + 425984;           // 128*256 (padded)
    short* Wll = ws16 + 458752;
    float* tpl = (float*)(ws16 + 491520); // transposed planes: 16515072 floats
    const size_t base_bytes = (size_t)491520 * 2 + (size_t)16515072 * 4;   // 67,043,328

    prep_weights<<<640, 64, 0, stream>>>(v1, g1, v2, g2, vl, gl,
                                         W1h, W1l, W2h, W2l, Wlh, Wll);

    // chunk size: 2304 bytes/point of feat (9 planes * 64 ch * (hi+lo) bf16)
    long long avail = (long long)ws_size - (long long)base_bytes;
    int CH = 0;
    if (avail > 0) {
        long long c = avail / 2304;
        if (c > 16384) c = 16384;           // cap: keeps chunk feat (37.7 MB) L3-resident
        CH = (int)(c & ~127LL);
    }

    if (CH >= 4096) {
        transpose_planes<<<4032, 256, 0, stream>>>(pls, tpl);
        short* fH = (short*)((char*)d_ws + base_bytes);   // [9][CH][64]
        short* fL = fH + (size_t)CH * 576;
        for (int p0 = 0; p0 < NPTS; p0 += CH) {
            int cnt = (NPTS - p0 < CH) ? (NPTS - p0) : CH;
            gather_kernel<<<cnt / 64, 256, 0, stream>>>(x, tpl, fH, fL, p0, CH);
            mlp_kernel<<<cnt / 128, 256, 0, stream>>>(fH, fL,
                                                      W1h, W1l, W2h, W2l, Wlh, Wll,
                                                      b1, b2, bl, (float*)d_out, p0, CH);
        }
    } else {
        const int use_t = (ws_size >= base_bytes) ? 1 : 0;
        if (use_t) transpose_planes<<<4032, 256, 0, stream>>>(pls, tpl);
        fused_kernel<<<NPTS / 128, 256, 0, stream>>>(x, pls, tpl, use_t,
                                                     W1h, W1l, W2h, W2l, Wlh, Wll,
                                                     b1, b2, bl, (float*)d_out);
    }
}

// Round 5
// 812.391 us; speedup vs baseline: 3.8761x; 3.8761x over previous
//
#include <hip/hip_runtime.h>
#include <math.h>

#define NPTS 131072

typedef short s16x8 __attribute__((ext_vector_type(8)));
typedef short s16x4 __attribute__((ext_vector_type(4)));
typedef float f32x4 __attribute__((ext_vector_type(4)));

struct Planes9 { const float* p[9]; };

__device__ __forceinline__ float sp100(float h) {
    float z = 100.0f * h;
    return (fmaxf(z, 0.0f) + log1pf(__expf(-fabsf(z)))) * 0.01f;
}

__device__ __forceinline__ short f2bf(float f) {
    union { float f; unsigned u; } a; a.f = f;
    unsigned u = a.u;
    return (short)((u + 0x7FFFu + ((u >> 16) & 1u)) >> 16);
}
__device__ __forceinline__ float bf2f(short h) {
    union { unsigned u; float f; } a; a.u = ((unsigned)(unsigned short)h) << 16;
    return a.f;
}

__device__ __forceinline__ f32x4 mm(s16x8 a, s16x8 b, f32x4 c) {
    return __builtin_amdgcn_mfma_f32_16x16x32_bf16(a, b, c, 0, 0, 0);
}

// ======================= point binning: Morton 16x16x16 =======================
__device__ __forceinline__ int spread3(int v) {   // 4 bits -> every 3rd bit
    return (v & 1) | ((v & 2) << 2) | ((v & 4) << 4) | ((v & 8) << 6);
}

__global__ __launch_bounds__(256) void bin_count(
    const float* __restrict__ x, int* __restrict__ hist, int* __restrict__ binOf)
{
    int p = blockIdx.x * 256 + threadIdx.x;
    float X = x[3*p+0], Y = x[3*p+1], Z = x[3*p+2];
    int bx = min(max((int)((X + 1.0f) * 8.0f), 0), 15);
    int by = min(max((int)((Y + 1.0f) * 8.0f), 0), 15);
    int bz = min(max((int)((Z + 1.0f) * 8.0f), 0), 15);
    int bin = spread3(bx) | (spread3(by) << 1) | (spread3(bz) << 2);
    binOf[p] = bin;
    atomicAdd(&hist[bin], 1);
}

__global__ __launch_bounds__(1024) void scan_bins(
    const int* __restrict__ hist, int* __restrict__ cursor)
{
    __shared__ int a[1024];
    int t = threadIdx.x;
    int h0 = hist[4*t+0], h1 = hist[4*t+1], h2 = hist[4*t+2], h3 = hist[4*t+3];
    int s = h0 + h1 + h2 + h3;
    a[t] = s;
    __syncthreads();
    #pragma unroll
    for (int off = 1; off < 1024; off <<= 1) {
        int v = a[t];
        if (t >= off) v += a[t - off];
        __syncthreads();
        a[t] = v;
        __syncthreads();
    }
    int base = a[t] - s;     // exclusive over 4-chunks
    cursor[4*t+0] = base;
    cursor[4*t+1] = base + h0;
    cursor[4*t+2] = base + h0 + h1;
    cursor[4*t+3] = base + h0 + h1 + h2;
}

__global__ __launch_bounds__(256) void scatter_pts(
    const int* __restrict__ binOf, int* __restrict__ cursor, int* __restrict__ perm)
{
    int p = blockIdx.x * 256 + threadIdx.x;
    int pos = atomicAdd(&cursor[binOf[p]], 1);
    perm[pos] = p;
}

// ---------------- planes (C,H,W) fp32 -> (H,W,C) bf16 ----------------
__global__ __launch_bounds__(256) void transpose_bf16(Planes9 pls, short* __restrict__ dst)
{
    __shared__ float tile[64 * 65];
    int b = blockIdx.x;
    int g = b / 1344, rem = b % 1344;
    int r, t2;
    if (rem < 64)       { r = 0; t2 = rem; }
    else if (rem < 320) { r = 1; t2 = rem - 64; }
    else                { r = 2; t2 = rem - 320; }
    int L = 64 << r;
    int wt = L >> 6;
    int y = t2 / wt, xt = t2 % wt;
    const float* sp = pls.p[g * 3 + r];
    short* dp = dst + (size_t)g * 5505024 + (r == 0 ? 0 : (r == 1 ? 262144 : 1310720));
    int t = threadIdx.x;
    int rowbase = y * L + xt * 64;
    {
        int xi = t & 63, cq = t >> 6;
        #pragma unroll
        for (int cc = 0; cc < 16; ++cc) {
            int c = cq * 16 + cc;
            tile[c * 65 + xi] = sp[(size_t)c * L * L + rowbase + xi];
        }
    }
    __syncthreads();
    {
        int ci = t & 63, xq = t >> 6;
        #pragma unroll
        for (int xx = 0; xx < 16; ++xx) {
            int xcol = xq * 16 + xx;
            dp[(size_t)(rowbase + xcol) * 64 + ci] = f2bf(tile[ci * 65 + xcol]);
        }
    }
}

// ======================= fused kernel v2: 128 pts/block, 4 waves =======================
// TPL=true: bf16 (H,W,C) planes + perm order. TPL=false: fp32 (C,H,W) fallback, identity.
template<bool TPL>
__global__ __launch_bounds__(256, 2) void fused2(
    const float* __restrict__ x, Planes9 pls, const short* __restrict__ tpl,
    const int* __restrict__ perm,
    const short* __restrict__ W1h, const short* __restrict__ W1l,
    const short* __restrict__ W2h, const short* __restrict__ W2l,
    const short* __restrict__ Wlh, const short* __restrict__ Wll,
    const float* __restrict__ b1, const float* __restrict__ b2, const float* __restrict__ bl,
    float* __restrict__ out)
{
    __shared__ __align__(16) char smem[65536];   // L1 feat-hi tile (16K) aliased under hB[128][256] bf16
    __shared__ float xs[384];
    const int t = threadIdx.x, blk = blockIdx.x;
    if (t < 128) {
        int pi = TPL ? perm[blk * 128 + t] : blk * 128 + t;
        xs[3*t+0] = x[3*pi+0];
        xs[3*t+1] = x[3*pi+1];
        xs[3*t+2] = x[3*pi+2];
    }
    const int w = t >> 6, ln = t & 63, s = ln & 15, g = ln >> 4;
    const int swz = (s & 7) << 4;
    const int pt = t & 127, kh = t >> 7;      // gather role: point, channel-half
    const int ptswz = (pt & 7) << 4;

    f32x4 acc[8][4];
    const f32x4 fz = {0.f, 0.f, 0.f, 0.f};
    #pragma unroll
    for (int mt = 0; mt < 8; ++mt)
        #pragma unroll
        for (int j = 0; j < 4; ++j) acc[mt][j] = fz;

    __syncthreads();

    // ================= Layer 1: 9 plane chunks, K=576, 2-term (Wh+Wl)*Bh =================
    #pragma unroll 1
    for (int pl = 0; pl < 9; ++pl) {
        const int grp = (pl >= 6) ? 2 : (pl >= 3 ? 1 : 0);
        const int r = pl - grp * 3;
        const int L = 64 << r;
        float u, v;
        { float xc0 = xs[pt*3+0], xc1 = xs[pt*3+1], xc2 = xs[pt*3+2];
          u = (grp == 2) ? xc1 : xc0;
          v = (grp == 0) ? xc1 : xc2; }
        float ix = (u + 1.0f) * 0.5f * (float)(L - 1);
        float iy = (v + 1.0f) * 0.5f * (float)(L - 1);
        float ix0 = floorf(ix), iy0 = floorf(iy);
        float wx = ix - ix0, wy = iy - iy0;
        int x0 = (int)fminf(fmaxf(ix0, 0.f), (float)(L-1));
        int x1 = (int)fminf(fmaxf(ix0+1.f, 0.f), (float)(L-1));
        int y0 = (int)fminf(fmaxf(iy0, 0.f), (float)(L-1));
        int y1 = (int)fminf(fmaxf(iy0+1.f, 0.f), (float)(L-1));
        float wnw = (1.f-wx)*(1.f-wy), wne = wx*(1.f-wy), wsw = (1.f-wx)*wy, wse = wx*wy;

        if (TPL) {
            const short* TP = tpl + (size_t)grp * 5505024
                            + (r == 0 ? 0u : (r == 1 ? 262144u : 1310720u));
            const short* pNW = TP + ((size_t)(y0*L + x0) * 64 + kh*32);
            const short* pNE = TP + ((size_t)(y0*L + x1) * 64 + kh*32);
            const short* pSW = TP + ((size_t)(y1*L + x0) * 64 + kh*32);
            const short* pSE = TP + ((size_t)(y1*L + x1) * 64 + kh*32);
            s16x8 cNW[4], cNE[4], cSW[4], cSE[4];
            #pragma unroll
            for (int q = 0; q < 4; ++q) {
                cNW[q] = *(const s16x8*)(pNW + q*8);
                cNE[q] = *(const s16x8*)(pNE + q*8);
                cSW[q] = *(const s16x8*)(pSW + q*8);
                cSE[q] = *(const s16x8*)(pSE + q*8);
            }
            #pragma unroll
            for (int q = 0; q < 4; ++q) {
                s16x8 hi8;
                #pragma unroll
                for (int e = 0; e < 8; ++e) {
                    float fnw = bf2f(cNW[q][e]), fne = bf2f(cNE[q][e]);
                    float fsw = bf2f(cSW[q][e]), fse = bf2f(cSE[q][e]);
                    hi8[e] = f2bf(wnw*fnw + wne*fne + wsw*fsw + wse*fse);
                }
                int off = pt*128 + ((kh*64 + q*16) ^ ptswz);
                *(s16x8*)(smem + off) = hi8;
            }
        } else {
            const float* P = pls.p[pl];
            const int i00 = y0*L+x0, i01 = y0*L+x1, i10 = y1*L+x0, i11 = y1*L+x1;
            float f[32];
            #pragma unroll 8
            for (int c = 0; c < 32; ++c) {
                const float* pc = P + (size_t)(kh*32 + c) * L * L;
                f[c] = wnw*pc[i00] + wne*pc[i01] + wsw*pc[i10] + wse*pc[i11];
            }
            #pragma unroll
            for (int q = 0; q < 4; ++q) {
                s16x8 hi8;
                #pragma unroll
                for (int e = 0; e < 8; ++e) hi8[e] = f2bf(f[q*8+e]);
                int off = pt*128 + ((kh*64 + q*16) ^ ptswz);
                *(s16x8*)(smem + off) = hi8;
            }
        }
        __syncthreads();

        #pragma unroll
        for (int ks = 0; ks < 2; ++ks) {
            s16x8 Ah[4], Al[4];
            #pragma unroll
            for (int j = 0; j < 4; ++j) {
                size_t ro = (size_t)((4*j + w)*16 + s) * 576 + (size_t)(pl*64 + ks*32 + g*8);
                Ah[j] = *(const s16x8*)(W1h + ro);
                Al[j] = *(const s16x8*)(W1l + ro);
            }
            #pragma unroll
            for (int mt = 0; mt < 8; ++mt) {
                int off = (mt*16 + s)*128 + ((ks*64 + g*16) ^ swz);
                s16x8 Bh = *(s16x8*)(smem + off);
                #pragma unroll
                for (int j = 0; j < 4; ++j) {
                    acc[mt][j] = mm(Ah[j], Bh, acc[mt][j]);
                    acc[mt][j] = mm(Al[j], Bh, acc[mt][j]);
                }
            }
        }
        __syncthreads();
    }

    // ======== bias + softplus, stage h1 (bf16) to hB [128 m][256 k] ========
    #pragma unroll
    for (int j = 0; j < 4; ++j) {
        f32x4 bv = *(const f32x4*)(b1 + (4*j + w)*16 + g*4);
        #pragma unroll
        for (int mt = 0; mt < 8; ++mt) {
            f32x4 a = acc[mt][j];
            s16x4 hq;
            hq[0] = f2bf(sp100(a[0] + bv[0]));
            hq[1] = f2bf(sp100(a[1] + bv[1]));
            hq[2] = f2bf(sp100(a[2] + bv[2]));
            hq[3] = f2bf(sp100(a[3] + bv[3]));
            int off = (mt*16 + s)*512 + ((((4*j + w)*32) + g*8) ^ swz);
            *(s16x4*)(smem + off) = hq;
        }
    }
    #pragma unroll
    for (int mt = 0; mt < 8; ++mt)
        #pragma unroll
        for (int j = 0; j < 4; ++j) acc[mt][j] = fz;
    __syncthreads();

    // ---------------- Layer 2: K = 256, split weights (2-term) ----------------
    #pragma unroll 1
    for (int ks = 0; ks < 8; ++ks) {
        s16x8 Ah[4], Al[4];
        #pragma unroll
        for (int j = 0; j < 4; ++j) {
            size_t ro = (size_t)((4*j + w)*16 + s) * 256 + (size_t)(ks*32 + g*8);
            Ah[j] = *(const s16x8*)(W2h + ro);
            Al[j] = *(const s16x8*)(W2l + ro);
        }
        #pragma unroll
        for (int mt = 0; mt < 8; ++mt) {
            int off = (mt*16 + s)*512 + ((ks*64 + g*16) ^ swz);
            s16x8 B = *(s16x8*)(smem + off);
            #pragma unroll
            for (int j = 0; j < 4; ++j) {
                acc[mt][j] = mm(Ah[j], B, acc[mt][j]);
                acc[mt][j] = mm(Al[j], B, acc[mt][j]);
            }
        }
    }
    __syncthreads();   // all hB reads done before overwrite with h2

    // ======== bias + softplus, stage h2 ========
    #pragma unroll
    for (int j = 0; j < 4; ++j) {
        f32x4 bv = *(const f32x4*)(b2 + (4*j + w)*16 + g*4);
        #pragma unroll
        for (int mt = 0; mt < 8; ++mt) {
            f32x4 a = acc[mt][j];
            s16x4 hq;
            hq[0] = f2bf(sp100(a[0] + bv[0]));
            hq[1] = f2bf(sp100(a[1] + bv[1]));
            hq[2] = f2bf(sp100(a[2] + bv[2]));
            hq[3] = f2bf(sp100(a[3] + bv[3]));
            int off = (mt*16 + s)*512 + ((((4*j + w)*32) + g*8) ^ swz);
            *(s16x4*)(smem + off) = hq;
        }
    }
    __syncthreads();

    // ---------------- Layer 3: Wl padded to 128 rows; wave w does tiles w, 4+w --------
    f32x4 acc3[8][2];
    #pragma unroll
    for (int mt = 0; mt < 8; ++mt) { acc3[mt][0] = fz; acc3[mt][1] = fz; }
    #pragma unroll 1
    for (int ks = 0; ks < 8; ++ks) {
        s16x8 Ah[2], Al[2];
        #pragma unroll
        for (int j = 0; j < 2; ++j) {
            size_t ro = (size_t)((4*j + w)*16 + s) * 256 + (size_t)(ks*32 + g*8);
            Ah[j] = *(const s16x8*)(Wlh + ro);
            Al[j] = *(const s16x8*)(Wll + ro);
        }
        #pragma unroll
        for (int mt = 0; mt < 8; ++mt) {
            int off = (mt*16 + s)*512 + ((ks*64 + g*16) ^ swz);
            s16x8 B = *(s16x8*)(smem + off);
            #pragma unroll
            for (int j = 0; j < 2; ++j) {
                acc3[mt][j] = mm(Ah[j], B, acc3[mt][j]);
                acc3[mt][j] = mm(Al[j], B, acc3[mt][j]);
            }
        }
    }

    // ---------------- output: feat (P,64) + dsdf (P,1), perm-scattered ----------------
    {
        f32x4 bv = *(const f32x4*)(bl + w*16 + g*4);
        #pragma unroll
        for (int mt = 0; mt < 8; ++mt) {
            int pl_ = blk*128 + mt*16 + s;
            size_t p = TPL ? (size_t)perm[pl_] : (size_t)pl_;
            f32x4 o = acc3[mt][0];
            o[0] += bv[0]; o[1] += bv[1]; o[2] += bv[2]; o[3] += bv[3];
            *(f32x4*)(out + p*64 + (size_t)(w*16 + g*4)) = o;
            if (w == 0 && g == 0)
                out[(size_t)NPTS*64 + p] = acc3[mt][1][0] + bl[64];
        }
    }
}

// ---------------- weight-norm + bf16 hi/lo split (row-major n x k) -------
__global__ __launch_bounds__(64) void prep_weights(
    const float* __restrict__ v1, const float* __restrict__ g1,
    const float* __restrict__ v2, const float* __restrict__ g2,
    const float* __restrict__ vl, const float* __restrict__ gl,
    short* __restrict__ W1h, short* __restrict__ W1l,
    short* __restrict__ W2h, short* __restrict__ W2l,
    short* __restrict__ Wlh, short* __restrict__ Wll)
{
    int i = blockIdx.x, t = threadIdx.x;
    const float* src; float gv; int K; short *dh, *dl; size_t ro;
    if (i < 256)      { src = v1 + (size_t)i*576; gv = g1[i]; K = 576; dh = W1h; dl = W1l; ro = (size_t)i*576; }
    else if (i < 512) { int rr = i-256; src = v2 + (size_t)rr*256; gv = g2[rr]; K = 256; dh = W2h; dl = W2l; ro = (size_t)rr*256; }
    else {
        int rr = i-512;
        K = 256; dh = Wlh; dl = Wll; ro = (size_t)rr*256;
        if (rr >= 65) {
            for (int k = t; k < 256; k += 64) { dh[ro+k] = 0; dl[ro+k] = 0; }
            return;
        }
        src = vl + (size_t)rr*256; gv = gl[rr];
    }
    float ssum = 0.f;
    for (int k = t; k < K; k += 64) { float wv = src[k]; ssum += wv*wv; }
    #pragma unroll
    for (int off = 32; off > 0; off >>= 1) ssum += __shfl_xor(ssum, off, 64);
    float sc = gv / sqrtf(ssum);
    for (int k = t; k < K; k += 64) {
        float wv = src[k] * sc;
        short hb = f2bf(wv);
        dh[ro + k] = hb;
        dl[ro + k] = f2bf(wv - bf2f(hb));
    }
}

extern "C" void kernel_launch(void* const* d_in, const int* in_sizes, int n_in,
                              void* d_out, int out_size, void* d_ws, size_t ws_size,
                              hipStream_t stream)
{
    const float* x = (const float*)d_in[0];
    Planes9 pls;
    for (int i = 0; i < 9; ++i) pls.p[i] = (const float*)d_in[1 + i];
    const float* v1 = (const float*)d_in[10];
    const float* g1 = (const float*)d_in[11];
    const float* b1 = (const float*)d_in[12];
    const float* v2 = (const float*)d_in[13];
    const float* g2 = (const float*)d_in[14];
    const float* b2 = (const float*)d_in[15];
    const float* vl = (const float*)d_in[16];
    const float* gl = (const float*)d_in[17];
    const float* bl = (const float*)d_in[18];

    short* ws16 = (short*)d_ws;
    short* W1h = ws16;                    // 256*576
    short* W1l = ws16 + 147456;
    short* W2h = ws16 + 294912;           // 256*256
    short* W2l = ws16 + 360448;
    short* Wlh = ws16 + 425984;           // 128*256 (padded)
    short* Wll = ws16 + 458752;
    short* tpl = ws16 + 491520;           // bf16 transposed planes: 16515072 shorts
    const size_t w_bytes   = (size_t)491520 * 2;                  //    983,040
    const size_t tpl_bytes = (size_t)16515072 * 2;                // 33,030,144
    int* hist   = (int*)((char*)d_ws + w_bytes + tpl_bytes);      // 4096
    int* cursor = hist + 4096;                                    // 4096
    int* binOf  = cursor + 4096;                                  // 131072
    int* perm   = binOf + 131072;                                 // 131072
    const size_t need = w_bytes + tpl_bytes + (4096*2 + 131072*2) * sizeof(int); // ~35.1 MB

    prep_weights<<<640, 64, 0, stream>>>(v1, g1, v2, g2, vl, gl,
                                         W1h, W1l, W2h, W2l, Wlh, Wll);

    if (ws_size >= need) {
        transpose_bf16<<<4032, 256, 0, stream>>>(pls, tpl);
        hipMemsetAsync(hist, 0, 4096 * sizeof(int), stream);
        bin_count<<<NPTS / 256, 256, 0, stream>>>(x, hist, binOf);
        scan_bins<<<1, 1024, 0, stream>>>(hist, cursor);
        scatter_pts<<<NPTS / 256, 256, 0, stream>>>(binOf, cursor, perm);
        fused2<true><<<NPTS / 128, 256, 0, stream>>>(x, pls, tpl, perm,
                                                     W1h, W1l, W2h, W2l, Wlh, Wll,
                                                     b1, b2, bl, (float*)d_out);
    } else {
        fused2<false><<<NPTS / 128, 256, 0, stream>>>(x, pls, (const short*)nullptr,
                                                      (const int*)nullptr,
                                                      W1h, W1l, W2h, W2l, Wlh, Wll,
                                                      b1, b2, bl, (float*)d_out);
    }
}

// Round 6
// 571.156 us; speedup vs baseline: 5.5132x; 1.4224x over previous
//
#include <hip/hip_runtime.h>
#include <hip/hip_bf16.h>
#include <math.h>

#define NPTS 131072

typedef short s16x8 __attribute__((ext_vector_type(8)));
typedef short s16x4 __attribute__((ext_vector_type(4)));
typedef float f32x4 __attribute__((ext_vector_type(4)));

struct Planes9 { const float* p[9]; };

__device__ __forceinline__ float sp100(float h) {
    float z = 100.0f * h;
    return (fmaxf(z, 0.0f) + log1pf(__expf(-fabsf(z)))) * 0.01f;
}

// exact-split rounding helpers (prep path)
__device__ __forceinline__ short f2bf(float f) {
    union { float f; unsigned u; } a; a.f = f;
    unsigned u = a.u;
    return (short)((u + 0x7FFFu + ((u >> 16) & 1u)) >> 16);
}
__device__ __forceinline__ float bf2f(short h) {
    union { unsigned u; float f; } a; a.u = ((unsigned)(unsigned short)h) << 16;
    return a.f;
}
// hot-path rounding: compiler cast -> v_cvt_pk_bf16_f32 (RNE, same bits as f2bf)
__device__ __forceinline__ short f2bf_fast(float f) {
    union { __hip_bfloat16 h; short s; } u;
    u.h = __float2bfloat16(f);
    return u.s;
}

__device__ __forceinline__ f32x4 mm(s16x8 a, s16x8 b, f32x4 c) {
    return __builtin_amdgcn_mfma_f32_16x16x32_bf16(a, b, c, 0, 0, 0);
}

// ======================= point binning: Morton 16x16x16 =======================
__device__ __forceinline__ int spread3(int v) {
    return (v & 1) | ((v & 2) << 2) | ((v & 4) << 4) | ((v & 8) << 6);
}

__global__ __launch_bounds__(256) void bin_count(
    const float* __restrict__ x, int* __restrict__ hist, int* __restrict__ binOf)
{
    int p = blockIdx.x * 256 + threadIdx.x;
    float X = x[3*p+0], Y = x[3*p+1], Z = x[3*p+2];
    int bx = min(max((int)((X + 1.0f) * 8.0f), 0), 15);
    int by = min(max((int)((Y + 1.0f) * 8.0f), 0), 15);
    int bz = min(max((int)((Z + 1.0f) * 8.0f), 0), 15);
    int bin = spread3(bx) | (spread3(by) << 1) | (spread3(bz) << 2);
    binOf[p] = bin;
    atomicAdd(&hist[bin], 1);
}

__global__ __launch_bounds__(1024) void scan_bins(
    const int* __restrict__ hist, int* __restrict__ cursor)
{
    __shared__ int a[1024];
    int t = threadIdx.x;
    int h0 = hist[4*t+0], h1 = hist[4*t+1], h2 = hist[4*t+2], h3 = hist[4*t+3];
    int s = h0 + h1 + h2 + h3;
    a[t] = s;
    __syncthreads();
    #pragma unroll
    for (int off = 1; off < 1024; off <<= 1) {
        int v = a[t];
        if (t >= off) v += a[t - off];
        __syncthreads();
        a[t] = v;
        __syncthreads();
    }
    int base = a[t] - s;
    cursor[4*t+0] = base;
    cursor[4*t+1] = base + h0;
    cursor[4*t+2] = base + h0 + h1;
    cursor[4*t+3] = base + h0 + h1 + h2;
}

__global__ __launch_bounds__(256) void scatter_pts(
    const int* __restrict__ binOf, int* __restrict__ cursor, int* __restrict__ perm)
{
    int p = blockIdx.x * 256 + threadIdx.x;
    int pos = atomicAdd(&cursor[binOf[p]], 1);
    perm[pos] = p;
}

// ---------------- planes (C,H,W) fp32 -> (H,W,C) bf16 ----------------
__global__ __launch_bounds__(256) void transpose_bf16(Planes9 pls, short* __restrict__ dst)
{
    __shared__ float tile[64 * 65];
    int b = blockIdx.x;
    int g = b / 1344, rem = b % 1344;
    int r, t2;
    if (rem < 64)       { r = 0; t2 = rem; }
    else if (rem < 320) { r = 1; t2 = rem - 64; }
    else                { r = 2; t2 = rem - 320; }
    int L = 64 << r;
    int wt = L >> 6;
    int y = t2 / wt, xt = t2 % wt;
    const float* sp = pls.p[g * 3 + r];
    short* dp = dst + (size_t)g * 5505024 + (r == 0 ? 0 : (r == 1 ? 262144 : 1310720));
    int t = threadIdx.x;
    int rowbase = y * L + xt * 64;
    {
        int xi = t & 63, cq = t >> 6;
        #pragma unroll
        for (int cc = 0; cc < 16; ++cc) {
            int c = cq * 16 + cc;
            tile[c * 65 + xi] = sp[(size_t)c * L * L + rowbase + xi];
        }
    }
    __syncthreads();
    {
        int ci = t & 63, xq = t >> 6;
        #pragma unroll
        for (int xx = 0; xx < 16; ++xx) {
            int xcol = xq * 16 + xx;
            dp[(size_t)(rowbase + xcol) * 64 + ci] = f2bf(tile[ci * 65 + xcol]);
        }
    }
}

// ======================= fused kernel v3: 64 pts/block, 4 waves, 4 blocks/CU ==========
template<bool TPL>
__global__ __launch_bounds__(256, 4) void fused3(
    const float* __restrict__ x, Planes9 pls, const short* __restrict__ tpl,
    const int* __restrict__ perm,
    const short* __restrict__ W1h, const short* __restrict__ W1l,
    const short* __restrict__ W2h, const short* __restrict__ W2l,
    const short* __restrict__ Wlh, const short* __restrict__ Wll,
    const float* __restrict__ b1, const float* __restrict__ b2, const float* __restrict__ bl,
    float* __restrict__ out)
{
    // hB [64 pt][256 k] bf16 (32 KB); L1 feat tile [64 pt][64 k] (8 KB) aliases low part
    __shared__ __align__(16) char smem[32768];
    __shared__ float xs[192];
    const int t = threadIdx.x, blk = blockIdx.x;
    if (t < 64) {
        int pi = TPL ? perm[blk * 64 + t] : blk * 64 + t;
        xs[3*t+0] = x[3*pi+0];
        xs[3*t+1] = x[3*pi+1];
        xs[3*t+2] = x[3*pi+2];
    }
    const int w = t >> 6, ln = t & 63, s = ln & 15, g = ln >> 4;
    const int swz = (s & 7) << 4;
    const int pt = t & 63, kh = t >> 6;       // gather: point, 16-channel quarter
    const int ptswz = (pt & 7) << 4;

    f32x4 acc[4][4];
    const f32x4 fz = {0.f, 0.f, 0.f, 0.f};
    #pragma unroll
    for (int mt = 0; mt < 4; ++mt)
        #pragma unroll
        for (int j = 0; j < 4; ++j) acc[mt][j] = fz;

    __syncthreads();

    // ================= Layer 1: 9 plane chunks, K=576, 2-term (Wh+Wl)*Bh =================
    #pragma unroll 1
    for (int pl = 0; pl < 9; ++pl) {
        const int grp = (pl >= 6) ? 2 : (pl >= 3 ? 1 : 0);
        const int r = pl - grp * 3;
        const int L = 64 << r;
        float u, v;
        { float xc0 = xs[pt*3+0], xc1 = xs[pt*3+1], xc2 = xs[pt*3+2];
          u = (grp == 2) ? xc1 : xc0;
          v = (grp == 0) ? xc1 : xc2; }
        float ix = (u + 1.0f) * 0.5f * (float)(L - 1);
        float iy = (v + 1.0f) * 0.5f * (float)(L - 1);
        float ix0 = floorf(ix), iy0 = floorf(iy);
        float wx = ix - ix0, wy = iy - iy0;
        int x0 = (int)fminf(fmaxf(ix0, 0.f), (float)(L-1));
        int x1 = (int)fminf(fmaxf(ix0+1.f, 0.f), (float)(L-1));
        int y0 = (int)fminf(fmaxf(iy0, 0.f), (float)(L-1));
        int y1 = (int)fminf(fmaxf(iy0+1.f, 0.f), (float)(L-1));
        float wnw = (1.f-wx)*(1.f-wy), wne = wx*(1.f-wy), wsw = (1.f-wx)*wy, wse = wx*wy;

        if (TPL) {
            const short* TP = tpl + (size_t)grp * 5505024
                            + (r == 0 ? 0u : (r == 1 ? 262144u : 1310720u));
            const short* pNW = TP + ((size_t)(y0*L + x0) * 64 + kh*16);
            const short* pNE = TP + ((size_t)(y0*L + x1) * 64 + kh*16);
            const short* pSW = TP + ((size_t)(y1*L + x0) * 64 + kh*16);
            const short* pSE = TP + ((size_t)(y1*L + x1) * 64 + kh*16);
            s16x8 cNW[2], cNE[2], cSW[2], cSE[2];
            #pragma unroll
            for (int q = 0; q < 2; ++q) {
                cNW[q] = *(const s16x8*)(pNW + q*8);
                cNE[q] = *(const s16x8*)(pNE + q*8);
                cSW[q] = *(const s16x8*)(pSW + q*8);
                cSE[q] = *(const s16x8*)(pSE + q*8);
            }
            #pragma unroll
            for (int q = 0; q < 2; ++q) {
                s16x8 hi8;
                #pragma unroll
                for (int e = 0; e < 8; ++e) {
                    float fnw = bf2f(cNW[q][e]), fne = bf2f(cNE[q][e]);
                    float fsw = bf2f(cSW[q][e]), fse = bf2f(cSE[q][e]);
                    hi8[e] = f2bf_fast(wnw*fnw + wne*fne + wsw*fsw + wse*fse);
                }
                int off = pt*128 + ((kh*32 + q*16) ^ ptswz);
                *(s16x8*)(smem + off) = hi8;
            }
        } else {
            const float* P = pls.p[pl];
            const int i00 = y0*L+x0, i01 = y0*L+x1, i10 = y1*L+x0, i11 = y1*L+x1;
            float f[16];
            #pragma unroll 8
            for (int c = 0; c < 16; ++c) {
                const float* pc = P + (size_t)(kh*16 + c) * L * L;
                f[c] = wnw*pc[i00] + wne*pc[i01] + wsw*pc[i10] + wse*pc[i11];
            }
            #pragma unroll
            for (int q = 0; q < 2; ++q) {
                s16x8 hi8;
                #pragma unroll
                for (int e = 0; e < 8; ++e) hi8[e] = f2bf_fast(f[q*8+e]);
                int off = pt*128 + ((kh*32 + q*16) ^ ptswz);
                *(s16x8*)(smem + off) = hi8;
            }
        }
        __syncthreads();

        #pragma unroll
        for (int ks = 0; ks < 2; ++ks) {
            s16x8 B[4];
            #pragma unroll
            for (int mt = 0; mt < 4; ++mt) {
                int off = (mt*16 + s)*128 + ((ks*64 + g*16) ^ swz);
                B[mt] = *(s16x8*)(smem + off);
            }
            #pragma unroll
            for (int j = 0; j < 4; ++j) {
                size_t ro = (size_t)((4*j + w)*16 + s) * 576 + (size_t)(pl*64 + ks*32 + g*8);
                s16x8 Ah = *(const s16x8*)(W1h + ro);
                s16x8 Al = *(const s16x8*)(W1l + ro);
                #pragma unroll
                for (int mt = 0; mt < 4; ++mt) {
                    acc[mt][j] = mm(Ah, B[mt], acc[mt][j]);
                    acc[mt][j] = mm(Al, B[mt], acc[mt][j]);
                }
            }
        }
        __syncthreads();
    }

    // ======== bias + softplus, stage h1 (bf16) to hB [64 pt][256 k] ========
    #pragma unroll
    for (int j = 0; j < 4; ++j) {
        f32x4 bv = *(const f32x4*)(b1 + (4*j + w)*16 + g*4);
        #pragma unroll
        for (int mt = 0; mt < 4; ++mt) {
            f32x4 a = acc[mt][j];
            s16x4 hq;
            hq[0] = f2bf_fast(sp100(a[0] + bv[0]));
            hq[1] = f2bf_fast(sp100(a[1] + bv[1]));
            hq[2] = f2bf_fast(sp100(a[2] + bv[2]));
            hq[3] = f2bf_fast(sp100(a[3] + bv[3]));
            int off = (mt*16 + s)*512 + ((((4*j + w)*32) + g*8) ^ swz);
            *(s16x4*)(smem + off) = hq;
        }
    }
    #pragma unroll
    for (int mt = 0; mt < 4; ++mt)
        #pragma unroll
        for (int j = 0; j < 4; ++j) acc[mt][j] = fz;
    __syncthreads();

    // ---------------- Layer 2: K = 256, split weights (2-term) ----------------
    #pragma unroll 1
    for (int ks = 0; ks < 8; ++ks) {
        s16x8 B[4];
        #pragma unroll
        for (int mt = 0; mt < 4; ++mt) {
            int off = (mt*16 + s)*512 + ((ks*64 + g*16) ^ swz);
            B[mt] = *(s16x8*)(smem + off);
        }
        #pragma unroll
        for (int j = 0; j < 4; ++j) {
            size_t ro = (size_t)((4*j + w)*16 + s) * 256 + (size_t)(ks*32 + g*8);
            s16x8 Ah = *(const s16x8*)(W2h + ro);
            s16x8 Al = *(const s16x8*)(W2l + ro);
            #pragma unroll
            for (int mt = 0; mt < 4; ++mt) {
                acc[mt][j] = mm(Ah, B[mt], acc[mt][j]);
                acc[mt][j] = mm(Al, B[mt], acc[mt][j]);
            }
        }
    }
    __syncthreads();   // all hB reads done before overwrite with h2

    // ======== bias + softplus, stage h2 ========
    #pragma unroll
    for (int j = 0; j < 4; ++j) {
        f32x4 bv = *(const f32x4*)(b2 + (4*j + w)*16 + g*4);
        #pragma unroll
        for (int mt = 0; mt < 4; ++mt) {
            f32x4 a = acc[mt][j];
            s16x4 hq;
            hq[0] = f2bf_fast(sp100(a[0] + bv[0]));
            hq[1] = f2bf_fast(sp100(a[1] + bv[1]));
            hq[2] = f2bf_fast(sp100(a[2] + bv[2]));
            hq[3] = f2bf_fast(sp100(a[3] + bv[3]));
            int off = (mt*16 + s)*512 + ((((4*j + w)*32) + g*8) ^ swz);
            *(s16x4*)(smem + off) = hq;
        }
    }
    __syncthreads();

    // ---------------- Layer 3: Wl padded to 128 rows; wave w does tiles w, 4+w --------
    f32x4 acc3[4][2];
    #pragma unroll
    for (int mt = 0; mt < 4; ++mt) { acc3[mt][0] = fz; acc3[mt][1] = fz; }
    #pragma unroll 1
    for (int ks = 0; ks < 8; ++ks) {
        s16x8 B[4];
        #pragma unroll
        for (int mt = 0; mt < 4; ++mt) {
            int off = (mt*16 + s)*512 + ((ks*64 + g*16) ^ swz);
            B[mt] = *(s16x8*)(smem + off);
        }
        #pragma unroll
        for (int j = 0; j < 2; ++j) {
            size_t ro = (size_t)((4*j + w)*16 + s) * 256 + (size_t)(ks*32 + g*8);
            s16x8 Ah = *(const s16x8*)(Wlh + ro);
            s16x8 Al = *(const s16x8*)(Wll + ro);
            #pragma unroll
            for (int mt = 0; mt < 4; ++mt) {
                acc3[mt][j] = mm(Ah, B[mt], acc3[mt][j]);
                acc3[mt][j] = mm(Al, B[mt], acc3[mt][j]);
            }
        }
    }

    // ---------------- output: feat (P,64) + dsdf (P,1), perm-scattered ----------------
    {
        f32x4 bv = *(const f32x4*)(bl + w*16 + g*4);
        #pragma unroll
        for (int mt = 0; mt < 4; ++mt) {
            int pl_ = blk*64 + mt*16 + s;
            size_t p = TPL ? (size_t)perm[pl_] : (size_t)pl_;
            f32x4 o = acc3[mt][0];
            o[0] += bv[0]; o[1] += bv[1]; o[2] += bv[2]; o[3] += bv[3];
            *(f32x4*)(out + p*64 + (size_t)(w*16 + g*4)) = o;
            if (w == 0 && g == 0)
                out[(size_t)NPTS*64 + p] = acc3[mt][1][0] + bl[64];
        }
    }
}

// ---------------- weight-norm + bf16 hi/lo split (row-major n x k) -------
__global__ __launch_bounds__(64) void prep_weights(
    const float* __restrict__ v1, const float* __restrict__ g1,
    const float* __restrict__ v2, const float* __restrict__ g2,
    const float* __restrict__ vl, const float* __restrict__ gl,
    short* __restrict__ W1h, short* __restrict__ W1l,
    short* __restrict__ W2h, short* __restrict__ W2l,
    short* __restrict__ Wlh, short* __restrict__ Wll)
{
    int i = blockIdx.x, t = threadIdx.x;
    const float* src; float gv; int K; short *dh, *dl; size_t ro;
    if (i < 256)      { src = v1 + (size_t)i*576; gv = g1[i]; K = 576; dh = W1h; dl = W1l; ro = (size_t)i*576; }
    else if (i < 512) { int rr = i-256; src = v2 + (size_t)rr*256; gv = g2[rr]; K = 256; dh = W2h; dl = W2l; ro = (size_t)rr*256; }
    else {
        int rr = i-512;
        K = 256; dh = Wlh; dl = Wll; ro = (size_t)rr*256;
        if (rr >= 65) {
            for (int k = t; k < 256; k += 64) { dh[ro+k] = 0; dl[ro+k] = 0; }
            return;
        }
        src = vl + (size_t)rr*256; gv = gl[rr];
    }
    float ssum = 0.f;
    for (int k = t; k < K; k += 64) { float wv = src[k]; ssum += wv*wv; }
    #pragma unroll
    for (int off = 32; off > 0; off >>= 1) ssum += __shfl_xor(ssum, off, 64);
    float sc = gv / sqrtf(ssum);
    for (int k = t; k < K; k += 64) {
        float wv = src[k] * sc;
        short hb = f2bf(wv);
        dh[ro + k] = hb;
        dl[ro + k] = f2bf(wv - bf2f(hb));
    }
}

extern "C" void kernel_launch(void* const* d_in, const int* in_sizes, int n_in,
                              void* d_out, int out_size, void* d_ws, size_t ws_size,
                              hipStream_t stream)
{
    const float* x = (const float*)d_in[0];
    Planes9 pls;
    for (int i = 0; i < 9; ++i) pls.p[i] = (const float*)d_in[1 + i];
    const float* v1 = (const float*)d_in[10];
    const float* g1 = (const float*)d_in[11];
    const float* b1 = (const float*)d_in[12];
    const float* v2 = (const float*)d_in[13];
    const float* g2 = (const float*)d_in[14];
    const float* b2 = (const float*)d_in[15];
    const float* vl = (const float*)d_in[16];
    const float* gl = (const float*)d_in[17];
    const float* bl = (const float*)d_in[18];

    short* ws16 = (short*)d_ws;
    short* W1h = ws16;                    // 256*576
    short* W1l = ws16 + 147456;
    short* W2h = ws16 + 294912;           // 256*256
    short* W2l = ws16 + 360448;
    short* Wlh = ws16 + 425984;           // 128*256 (padded)
    short* Wll = ws16 + 458752;
    short* tpl = ws16 + 491520;           // bf16 transposed planes: 16515072 shorts
    const size_t w_bytes   = (size_t)491520 * 2;
    const size_t tpl_bytes = (size_t)16515072 * 2;
    int* hist   = (int*)((char*)d_ws + w_bytes + tpl_bytes);
    int* cursor = hist + 4096;
    int* binOf  = cursor + 4096;
    int* perm   = binOf + 131072;
    const size_t need = w_bytes + tpl_bytes + (4096*2 + 131072*2) * sizeof(int);

    prep_weights<<<640, 64, 0, stream>>>(v1, g1, v2, g2, vl, gl,
                                         W1h, W1l, W2h, W2l, Wlh, Wll);

    if (ws_size >= need) {
        transpose_bf16<<<4032, 256, 0, stream>>>(pls, tpl);
        hipMemsetAsync(hist, 0, 4096 * sizeof(int), stream);
        bin_count<<<NPTS / 256, 256, 0, stream>>>(x, hist, binOf);
        scan_bins<<<1, 1024, 0, stream>>>(hist, cursor);
        scatter_pts<<<NPTS / 256, 256, 0, stream>>>(binOf, cursor, perm);
        fused3<true><<<NPTS / 64, 256, 0, stream>>>(x, pls, tpl, perm,
                                                    W1h, W1l, W2h, W2l, Wlh, Wll,
                                                    b1, b2, bl, (float*)d_out);
    } else {
        fused3<false><<<NPTS / 64, 256, 0, stream>>>(x, pls, (const short*)nullptr,
                                                     (const int*)nullptr,
                                                     W1h, W1l, W2h, W2l, Wlh, Wll,
                                                     b1, b2, bl, (float*)d_out);
    }
}